// Round 7
// baseline (273.112 us; speedup 1.0000x reference)
//
#include <hip/hip_runtime.h>

#define NPOS 65536   // 256*256

typedef __attribute__((ext_vector_type(8))) short bf16x8;
typedef __attribute__((ext_vector_type(4))) float f32x4;

#if __has_builtin(__builtin_amdgcn_exp2f)
#define EXP2F(x) __builtin_amdgcn_exp2f(x)
#else
#define EXP2F(x) __expf((x) * 0.6931471805599453f)
#endif
#if __has_builtin(__builtin_amdgcn_rcpf)
#define RCPF(x) __builtin_amdgcn_rcpf(x)
#else
#define RCPF(x) (1.0f / (x))
#endif

static __device__ __forceinline__ unsigned short f2bf(float f) {
  union { float f; unsigned int u; } v; v.f = f;
  unsigned int r = v.u + 0x7fffu + ((v.u >> 16) & 1u);
  return (unsigned short)(r >> 16);
}
static __device__ __forceinline__ float bf2f(unsigned short u) {
  union { unsigned int u; float f; } v; v.u = ((unsigned int)u) << 16;
  return v.f;
}
static __device__ __forceinline__ float lo_bf(unsigned int u) {
  union { unsigned int u; float f; } v; v.u = u << 16; return v.f;
}
static __device__ __forceinline__ float hi_bf(unsigned int u) {
  union { unsigned int u; float f; } v; v.u = u & 0xffff0000u; return v.f;
}
static __device__ __forceinline__ unsigned int pack2(float a, float b) {
  return (unsigned int)f2bf(a) | ((unsigned int)f2bf(b) << 16);
}
// (hi.bf16_trunc << 16) | lo.bf16_trunc  — 1 instruction (v_perm_b32)
static __device__ __forceinline__ unsigned int permpack(float hi, float lo) {
  union { float f; unsigned int u; } a, b;
  a.f = hi; b.f = lo;
#if __has_builtin(__builtin_amdgcn_perm)
  return __builtin_amdgcn_perm(a.u, b.u, 0x07060302u);
#else
  return (a.u & 0xffff0000u) | (b.u >> 16);
#endif
}

// ---------------- K0: pack transposed bf16 weights ----------------
// Wq gets 1/sqrt(32)*log2(e) folded (softmax uses exp2, no max-sub).
__global__ void k_pack(const float* __restrict__ Wq, const float* __restrict__ Wk,
                       const float* __restrict__ Wv, const float* __restrict__ Wg,
                       const float* __restrict__ Wo,
                       ushort* __restrict__ WT, ushort* __restrict__ WoT) {
  int idx = blockIdx.x * blockDim.x + threadIdx.x;
  if (idx < 512 * 128) {
    int n = idx >> 7, k = idx & 127;
    int nn = n & 127;
    float val;
    if (n < 128)      val = Wq[k * 128 + nn] * (0.17677669529663687f * 1.4426950408889634f);
    else if (n < 256) val = Wk[k * 128 + nn];
    else if (n < 384) val = Wv[k * 128 + nn];
    else              val = Wg[k * 128 + nn];
    WT[idx] = f2bf(val);
  } else if (idx < 512 * 128 + 128 * 128) {
    int j = idx - 512 * 128;
    int n = j >> 7, k = j & 127;
    WoT[j] = f2bf(Wo[k * 128 + n]);
  }
}

// ---------------- K1: fused LN + bias + QKVG proj; no barriers --------------
// block = 32 rows (grid 2048); wave = 16 rows.
__global__ __launch_bounds__(128, 4) void k_lnproj(
    const float* __restrict__ in, const float* __restrict__ gamma,
    const float* __restrict__ beta, const float* __restrict__ Wb,
    const ushort* __restrict__ WT, const float* __restrict__ bg,
    ushort* __restrict__ q, ushort* __restrict__ kmat, ushort* __restrict__ vT,
    ushort* __restrict__ gate, ushort* __restrict__ biasB) {
  __shared__ __align__(16) ushort stg[2][3072];   // 6 KB per-wave staging
  int t = threadIdx.x, wv = t >> 6, lane = t & 63;
  int n = lane & 15, g = lane >> 4;
  int row0 = blockIdx.x * 32;
  int i = row0 >> 8, j0b = row0 & 255;
  int m0 = wv * 16;
  int myrow = row0 + m0 + n;
  const float* rp = in + (size_t)myrow * 128;

  // ---- LN in registers ----
  float xv[32];
  float s = 0.f, ss = 0.f;
  #pragma unroll
  for (int kc = 0; kc < 4; kc++)
    #pragma unroll
    for (int pr = 0; pr < 2; pr++) {
      float4 v = *(const float4*)(rp + kc * 32 + g * 8 + pr * 4);
      int o = kc * 8 + pr * 4;
      xv[o] = v.x; xv[o+1] = v.y; xv[o+2] = v.z; xv[o+3] = v.w;
      s  += v.x + v.y + v.z + v.w;
      ss += v.x*v.x + v.y*v.y + v.z*v.z + v.w*v.w;
    }
  s  += __shfl_xor(s, 16, 64);  s  += __shfl_xor(s, 32, 64);
  ss += __shfl_xor(ss, 16, 64); ss += __shfl_xor(ss, 32, 64);
  float mu  = s * (1.0f / 128.0f);
  float var = ss * (1.0f / 128.0f) - mu * mu;
  float rs  = rsqrtf(var + 1e-5f);
  float p0 = 0.f, p1 = 0.f, p2 = 0.f, p3 = 0.f;
  #pragma unroll
  for (int kc = 0; kc < 4; kc++)
    #pragma unroll
    for (int pr = 0; pr < 2; pr++) {
      int c0 = kc * 32 + g * 8 + pr * 4;
      float4 g4 = *(const float4*)(gamma + c0);
      float4 b4 = *(const float4*)(beta + c0);
      int o = kc * 8 + pr * 4;
      #pragma unroll
      for (int r = 0; r < 4; r++) {
        float xn = (xv[o + r] - mu) * rs * (&g4.x)[r] + (&b4.x)[r];
        xv[o + r] = xn;
        float4 w = ((const float4*)Wb)[c0 + r];
        p0 += xn * w.x; p1 += xn * w.y; p2 += xn * w.z; p3 += xn * w.w;
      }
    }
  p0 += __shfl_xor(p0, 16, 64); p0 += __shfl_xor(p0, 32, 64);
  p1 += __shfl_xor(p1, 16, 64); p1 += __shfl_xor(p1, 32, 64);
  p2 += __shfl_xor(p2, 16, 64); p2 += __shfl_xor(p2, 32, 64);
  p3 += __shfl_xor(p3, 16, 64); p3 += __shfl_xor(p3, 32, 64);
  if (g == 0) {
    const float l2e = 1.4426950408889634f;
    biasB[0 * NPOS + myrow] = f2bf(p0 * l2e);
    biasB[1 * NPOS + myrow] = f2bf(p1 * l2e);
    biasB[2 * NPOS + myrow] = f2bf(p2 * l2e);
    biasB[3 * NPOS + myrow] = f2bf(p3 * l2e);
  }
  bf16x8 a[4];
  #pragma unroll
  for (int kc = 0; kc < 4; kc++)
    #pragma unroll
    for (int e = 0; e < 8; e++) a[kc][e] = (short)f2bf(xv[kc * 8 + e]);

  ushort* st = stg[wv];
  // ---- 4 sections: q | k | v | gate (kc-outer, 8-deep load batches) ----
  #pragma unroll
  for (int s4 = 0; s4 < 4; s4++) {
    f32x4 acc[8];
    #pragma unroll
    for (int ntl = 0; ntl < 8; ntl++) acc[ntl] = (f32x4){0.f, 0.f, 0.f, 0.f};
    #pragma unroll
    for (int kc = 0; kc < 4; kc++) {
      bf16x8 b8[8];
      #pragma unroll
      for (int ntl = 0; ntl < 8; ntl++)
        b8[ntl] = *(const bf16x8*)(WT + (size_t)(s4 * 128 + ntl * 16 + n) * 128 + kc * 32 + g * 8);
      #pragma unroll
      for (int ntl = 0; ntl < 8; ntl++)
        acc[ntl] = __builtin_amdgcn_mfma_f32_16x16x32_bf16(a[kc], b8[ntl], acc[ntl], 0, 0, 0);
    }
    if (s4 == 2) {
      // V: stage transposed [128 hd][24 k-slot]
      #pragma unroll
      for (int ntl = 0; ntl < 8; ntl++) {
        uint2 vp;
        vp.x = pack2(acc[ntl][0], acc[ntl][1]);
        vp.y = pack2(acc[ntl][2], acc[ntl][3]);
        *(uint2*)(&st[(ntl * 16 + n) * 24 + g * 4]) = vp;
      }
      #pragma unroll
      for (int it = 0; it < 4; it++) {
        int c = it * 64 + lane;
        int hd = c >> 1, half = c & 1;
        bf16x8 vv = *(const bf16x8*)(&st[hd * 24 + half * 8]);
        int h = hd >> 5, d = hd & 31;
        *(bf16x8*)(vT + ((size_t)(i * 4 + h) * 32 + d) * 256 + j0b + m0 + half * 8) = vv;
      }
    } else {
      #pragma unroll
      for (int ntl = 0; ntl < 8; ntl++) {
        #pragma unroll
        for (int r = 0; r < 4; r++) {
          float val = acc[ntl][r];
          if (s4 == 3) val = 1.0f / (1.0f + __expf(-(val + bg[ntl * 16 + n])));
          st[(g * 4 + r) * 136 + ntl * 16 + n] = f2bf(val);
        }
      }
      if (s4 == 3) {
        #pragma unroll
        for (int it = 0; it < 4; it++) {
          int c = it * 64 + lane;
          int row = c >> 4, off = (c & 15) * 8;
          *(bf16x8*)(gate + (size_t)(row0 + m0 + row) * 128 + off) =
              *(const bf16x8*)(&st[row * 136 + off]);
        }
      } else {
        ushort* dst = (s4 == 0) ? q : kmat;
        int row = lane >> 2, off = (lane & 3) * 8;
        #pragma unroll
        for (int h = 0; h < 4; h++)
          *(bf16x8*)(dst + ((size_t)(i * 4 + h) * 256 + j0b + m0 + row) * 32 + off) =
              *(const bf16x8*)(&st[row * 136 + h * 32 + off]);
      }
    }
  }
}

// ---------------- K2: fused attention + out-proj + residual -----------------
// block = (i = bx>>2, jq = bx&3); wave = 16 query rows, all 4 heads; no barriers.
#define AST 136    // ctx A-stage row stride (ushorts)
#define PST 40     // P-stage row stride (ushorts)
#define WST 4224   // per-wave stage (ushorts) = 8448 B (f32 drain overlays all)
__global__ __launch_bounds__(256, 4) void k_attn2(
    const ushort* __restrict__ q, const ushort* __restrict__ kmat,
    const ushort* __restrict__ vT, const ushort* __restrict__ gate,
    const ushort* __restrict__ biasB, const ushort* __restrict__ WoT,
    const float* __restrict__ bo, const float* __restrict__ in0,
    float* __restrict__ out) {
  __shared__ __align__(16) ushort stg[4][WST];
  int i = blockIdx.x >> 2, jq = blockIdx.x & 3;
  int t = threadIdx.x, wv = t >> 6, lane = t & 63;
  int n = lane & 15, g = lane >> 4;
  int j0 = jq * 64 + wv * 16;
  ushort* Ast = stg[wv];            // [16 q-rows][128 ch] bf16, stride AST
  ushort* Pw  = stg[wv] + 2176;     // [16 q-rows][32 keys] bf16, stride PST
  float*  CT  = (float*)stg[wv];    // f32 drain stage, stride 132 (overlays)

  const ushort* qi = q    + (size_t)i * 4 * 8192;
  const ushort* ki = kmat + (size_t)i * 4 * 8192;
  const ushort* vi = vT   + (size_t)i * 4 * 8192;

  // ---- per-head attention, ctx staged into Ast ----
  #pragma unroll
  for (int h = 0; h < 4; h++) {
    const ushort* kb = ki + h * 8192;
    const ushort* vb = vi + h * 8192;
    const ushort* bb = biasB + (size_t)h * NPOS;
    bf16x8 bq = *(const bf16x8*)(qi + h * 8192 + (size_t)(j0 + n) * 32 + g * 8);
    // S^T tiles: A=K (rows=key), B=Q (cols=query); bias preloaded into C
    f32x4 s[16];
    #pragma unroll
    for (int kt = 0; kt < 16; kt++) {
      uint2 bv = *(const uint2*)(bb + (size_t)(j0 + n) * 256 + kt * 16 + g * 4);
      bf16x8 ak = *(const bf16x8*)(kb + (size_t)(kt * 16 + n) * 32 + g * 8);
      f32x4 c;
      c[0] = lo_bf(bv.x); c[1] = hi_bf(bv.x);
      c[2] = lo_bf(bv.y); c[3] = hi_bf(bv.y);
      s[kt] = __builtin_amdgcn_mfma_f32_16x16x32_bf16(ak, bq, c, 0, 0, 0);
    }
    // softmax: exp2 (log2e folded into Wq & bias), no max-sub (scores bounded)
    f32x4 a4 = {0.f, 0.f, 0.f, 0.f};
    #pragma unroll
    for (int kt = 0; kt < 16; kt++) {
      #pragma unroll
      for (int r = 0; r < 4; r++) s[kt][r] = EXP2F(s[kt][r]);
      a4 += s[kt];
    }
    float sm = (a4[0] + a4[1]) + (a4[2] + a4[3]);
    sm += __shfl_xor(sm, 16, 64);
    sm += __shfl_xor(sm, 32, 64);
    float inv = RCPF(sm);
    // PV interleaved with P staging (wave-private LDS, in-order DS pipe)
    f32x4 ctx0 = {0.f, 0.f, 0.f, 0.f}, ctx1 = {0.f, 0.f, 0.f, 0.f};
    #pragma unroll
    for (int c8 = 0; c8 < 8; c8++) {
      #pragma unroll
      for (int t2 = 0; t2 < 2; t2++) {
        int kt = c8 * 2 + t2;
        uint2 pp;
        pp.x = permpack(s[kt][1] * inv, s[kt][0] * inv);
        pp.y = permpack(s[kt][3] * inv, s[kt][2] * inv);
        *(uint2*)(&Pw[n * PST + t2 * 16 + g * 4]) = pp;
      }
      bf16x8 ap = *(const bf16x8*)(&Pw[n * PST + g * 8]);
      bf16x8 v0 = *(const bf16x8*)(vb + (size_t)n * 256 + c8 * 32 + g * 8);
      bf16x8 v1 = *(const bf16x8*)(vb + (size_t)(16 + n) * 256 + c8 * 32 + g * 8);
      ctx0 = __builtin_amdgcn_mfma_f32_16x16x32_bf16(ap, v0, ctx0, 0, 0, 0);
      ctx1 = __builtin_amdgcn_mfma_f32_16x16x32_bf16(ap, v1, ctx1, 0, 0, 0);
    }
    // stage ctx (C-layout: col=query n, row=d) into Ast A-layout [query][ch]
    uint2 c0, c1;
    c0.x = pack2(ctx0[0], ctx0[1]); c0.y = pack2(ctx0[2], ctx0[3]);
    c1.x = pack2(ctx1[0], ctx1[1]); c1.y = pack2(ctx1[2], ctx1[3]);
    *(uint2*)(&Ast[n * AST + h * 32 + g * 4])      = c0;
    *(uint2*)(&Ast[n * AST + h * 32 + 16 + g * 4]) = c1;
  }

  // ---- out-projection: A = gate * ctx (A-frag via LDS), B = WoT ----
  f32x4 acc[8];
  #pragma unroll
  for (int ntl = 0; ntl < 8; ntl++) acc[ntl] = (f32x4){0.f, 0.f, 0.f, 0.f};
  #pragma unroll
  for (int kc = 0; kc < 4; kc++) {
    bf16x8 ap = *(const bf16x8*)(&Ast[n * AST + kc * 32 + g * 8]);
    bf16x8 gt = *(const bf16x8*)(gate + ((size_t)i * 256 + j0 + n) * 128 + kc * 32 + g * 8);
    bf16x8 af;
    #pragma unroll
    for (int e = 0; e < 8; e++)
      af[e] = (short)f2bf(bf2f((unsigned short)ap[e]) * bf2f((unsigned short)gt[e]));
    bf16x8 b8[8];
    #pragma unroll
    for (int ntl = 0; ntl < 8; ntl++)
      b8[ntl] = *(const bf16x8*)(WoT + (size_t)(ntl * 16 + n) * 128 + kc * 32 + g * 8);
    #pragma unroll
    for (int ntl = 0; ntl < 8; ntl++)
      acc[ntl] = __builtin_amdgcn_mfma_f32_16x16x32_bf16(af, b8[ntl], acc[ntl], 0, 0, 0);
  }
  // ---- epilogue: bias, stage f32, coalesced residual+store ----
  #pragma unroll
  for (int ntl = 0; ntl < 8; ntl++) {
    float bov = bo[ntl * 16 + n];
    #pragma unroll
    for (int r = 0; r < 4; r++)
      CT[(g * 4 + r) * 132 + ntl * 16 + n] = acc[ntl][r] + bov;
  }
  #pragma unroll
  for (int it = 0; it < 8; it++) {
    int c = it * 64 + lane;
    int row = c >> 5, off = (c & 31) * 4;
    f32x4 v = *(const f32x4*)(&CT[row * 132 + off]);
    size_t o = ((size_t)i * 256 + j0 + row) * 128 + off;
    f32x4 r4 = *(const f32x4*)(in0 + o);
    v[0] += r4[0]; v[1] += r4[1]; v[2] += r4[2]; v[3] += r4[3];
    *(f32x4*)(out + o) = v;
  }
}

extern "C" void kernel_launch(void* const* d_in, const int* in_sizes, int n_in,
                              void* d_out, int out_size, void* d_ws, size_t ws_size,
                              hipStream_t stream) {
  const float* in0   = (const float*)d_in[0];
  const float* gamma = (const float*)d_in[1];
  const float* beta  = (const float*)d_in[2];
  const float* Wq    = (const float*)d_in[3];
  const float* Wk    = (const float*)d_in[4];
  const float* Wv    = (const float*)d_in[5];
  const float* Wb    = (const float*)d_in[6];
  const float* Wg    = (const float*)d_in[7];
  const float* bg    = (const float*)d_in[8];
  const float* Wo    = (const float*)d_in[9];
  const float* bo    = (const float*)d_in[10];
  float* out = (float*)d_out;
  char* ws = (char*)d_ws;

  const size_t MB = 1024 * 1024;
  ushort* qbuf  = (ushort*)(ws);              // 16 MB: [ih][j][d]
  ushort* kbuf  = (ushort*)(ws + 16 * MB);    // 16 MB: [ih][k][d]
  ushort* vTbuf = (ushort*)(ws + 32 * MB);    // 16 MB: [ih][d][k]
  ushort* gbuf  = (ushort*)(ws + 48 * MB);    // 16 MB: gate [pos][128]
  ushort* biasB = (ushort*)(ws + 64 * MB);    // 512 KB: [h][j*256+k] * log2e
  ushort* WT    = (ushort*)(ws + 65 * MB);    // 128 KB
  ushort* WoT   = (ushort*)(ws + 65 * MB + 128 * 1024);  // 32 KB

  k_pack  <<<320, 256, 0, stream>>>(Wq, Wk, Wv, Wg, Wo, WT, WoT);
  k_lnproj<<<2048, 128, 0, stream>>>(in0, gamma, beta, Wb, WT, bg,
                                     qbuf, kbuf, vTbuf, gbuf, biasB);
  k_attn2 <<<1024, 256, 0, stream>>>(qbuf, kbuf, vTbuf, gbuf, biasB,
                                     WoT, bo, in0, out);
}